// Round 5
// baseline (257.685 us; speedup 1.0000x reference)
//
#include <hip/hip_runtime.h>

// GraphSAGE encoder: N=100000, E=1600000, D=64. fp32 in/out, bf16 internal.
// relu(Wl@mean(x) + Wr@x + b) == relu(mean(Wl@x) + (Wr@x + b))  [linearity]
// Round-14: round-13 kept binA_xf at 58us -- counters showed Occ 14%/VALU 6%/
// HBM 15%: the bin tail ran at 1 block/CU (4 waves) after xform drained. Fix:
// whole fused kernel goes to 1024-thread blocks (16 waves/CU for the bin
// path, the occupancy the original 38us two-pass binA had) while keeping the
// single-pass cell structure (halved memory work). Xform path is wave-
// granular grid-stride, unchanged math. 88 VGPR: 4 waves/SIMD x 88 = 352
// fits the 512-reg file.
//   k_binA_xf  : [blocks 0..NBINA)  single-pass edge binning into cells
//                [blocks NBINA..)   y1||z1 = bf16(x) @ bf16([W1l;W1r])^T
//   k_binB     : per-bucket padded-CSR slice in LDS (32KB), streamed coalesced
//   k_aggr     : h = relu(mean_nbr(y) + z) in-place on z, all bf16 rows
//   k_xform_b16: y2||z2 = h1 @ bf16([W2l;W2r])^T (in-place z)
//   k_out      : logits = h2 @ Wout^T + bout; log_softmax -> d_out (fp32)

#define TB 256
#define TBF 1024   // fused-kernel block size (16 waves)
#define NBINA 256  // bin blocks (== TB so binB can go thread-per-cell)
#define XFB 256    // xform blocks in k_binA_xf (16 waves each -> 4096 waves)
#define CAPC 32    // slots per (bucket,block) cell: mean 8, P(>32)~1e-12
#define NBPAD 1024

typedef __attribute__((ext_vector_type(8))) short bf16x8;
typedef __attribute__((ext_vector_type(4))) float f32x4;
typedef __attribute__((ext_vector_type(2))) float f32x2;

__device__ __forceinline__ unsigned short bf16c(float f) {
  union { float f; unsigned u; } v; v.f = f;
  unsigned r = (v.u + 0x7FFFu + ((v.u >> 16) & 1u)) >> 16;  // RNE
  return (unsigned short)r;
}

__device__ __forceinline__ bf16x8 ld_bf8(const float* p) {
  float4 a = *(const float4*)p;
  float4 b = *(const float4*)(p + 4);
  bf16x8 r;
  r[0] = bf16c(a.x); r[1] = bf16c(a.y); r[2] = bf16c(a.z); r[3] = bf16c(a.w);
  r[4] = bf16c(b.x); r[5] = bf16c(b.y); r[6] = bf16c(b.z); r[7] = bf16c(b.w);
  return r;
}

__device__ __forceinline__ float bflo(unsigned u) { return __uint_as_float(u << 16); }
__device__ __forceinline__ float bfhi(unsigned u) { return __uint_as_float(u & 0xFFFF0000u); }
__device__ __forceinline__ unsigned bfpk(float lo, float hi) {
  return (unsigned)bf16c(lo) | ((unsigned)bf16c(hi) << 16);
}

// ---- fused: single-pass binning (blocks < NBINA) || layer-1 transform.
__global__ __launch_bounds__(1024) void k_binA_xf(
    const int* __restrict__ ei, int E,
    int* __restrict__ cellcnt, unsigned int* __restrict__ bucketData, int NB,
    const float* __restrict__ xin, const float* __restrict__ Wl,
    const float* __restrict__ Wr, const float* __restrict__ bl,
    unsigned short* __restrict__ y, unsigned short* __restrict__ zout, int n) {
  if (blockIdx.x < NBINA) {
    __shared__ int lcnt[NBPAD];
    __shared__ int s_nz;
    if (threadIdx.x == 0) s_nz = 0;
    for (int i = threadIdx.x; i < NBPAD; i += TBF) lcnt[i] = 0;
    __syncthreads();
    int nz = 0;
    for (int i = threadIdx.x; i < 2048; i += TBF) nz |= ei[2 * i + 1];
    if (nz) atomicOr(&s_nz, 1);
    __syncthreads();
    bool m64 = (s_nz == 0);  // int64 layout
    int bb = blockIdx.x;

    long long e0 = (long long)E * bb / NBINA;
    long long e1 = (long long)E * (bb + 1) / NBINA;
    for (long long e = e0 + threadIdx.x; e < e1; e += TBF) {
      int src, dst;
      if (m64) {
        src = ((const int2*)ei)[e].x;
        dst = ((const int2*)ei)[(long long)E + e].x;
      } else {
        src = ei[e];
        dst = ei[(long long)E + e];
      }
      int b = dst >> 7;
      int pos = atomicAdd(&lcnt[b], 1);
      if (pos < CAPC)
        bucketData[((size_t)b * NBINA + bb) * CAPC + pos] =
            ((unsigned)(dst & 127) << 24) | (unsigned)src;
    }
    __syncthreads();
    // coalesced: block bb owns contiguous row cellcnt[bb*NBPAD + 0..NB)
    for (int b = threadIdx.x; b < NB; b += TBF) cellcnt[bb * NBPAD + b] = lcnt[b];
    return;
  }

  // ---- layer-1 transform: y||z = bf16(x fp32) @ bf16([Wl;Wr])^T; y,z bf16.
  // Wave = 16-node tile, grid-stride. D layout (m89): feat=lane&15, node=quad*4+reg.
  int lane = threadIdx.x & 63;
  int quad = lane >> 4, m = lane & 15;
  int w0 = ((blockIdx.x - NBINA) * TBF + threadIdx.x) >> 6;
  int nw = (XFB * TBF) >> 6;

  bf16x8 bfrag[8][2];
  float bias[4];
#pragma unroll
  for (int t = 0; t < 8; ++t) {
    const float* W = (t < 4) ? Wl : Wr;
    int row = (t & 3) * 16 + m;
#pragma unroll
    for (int s = 0; s < 2; ++s)
      bfrag[t][s] = ld_bf8(W + row * 64 + s * 32 + quad * 8);
  }
#pragma unroll
  for (int t = 0; t < 4; ++t) bias[t] = bl[t * 16 + m];

  int nT = (n + 15) >> 4;
  for (int tile = w0; tile < nT; tile += nw) {
    int node0 = tile << 4;
    int mrow = node0 + m;
    if (mrow >= n) mrow = n - 1;
    const float* xr = xin + (size_t)mrow * 64;
    bf16x8 a0 = ld_bf8(xr + quad * 8);
    bf16x8 a1 = ld_bf8(xr + 32 + quad * 8);

    f32x4 acc[8];
#pragma unroll
    for (int t = 0; t < 8; ++t) {
      f32x4 z4 = {0.f, 0.f, 0.f, 0.f};
      z4 = __builtin_amdgcn_mfma_f32_16x16x32_bf16(a0, bfrag[t][0], z4, 0, 0, 0);
      acc[t] = __builtin_amdgcn_mfma_f32_16x16x32_bf16(a1, bfrag[t][1], z4, 0, 0, 0);
    }

#pragma unroll
    for (int r = 0; r < 4; ++r) {
      int node = node0 + quad * 4 + r;
      if (node >= n) break;
      size_t rb = (size_t)node * 64 + m;
#pragma unroll
      for (int t = 0; t < 4; ++t) y[rb + t * 16] = bf16c(acc[t][r]);
#pragma unroll
      for (int t = 0; t < 4; ++t) zout[rb + t * 16] = bf16c(acc[t + 4][r] + bias[t]);
    }
  }
}

// ---- phase B: drain cells thread-per-cell into the bucket's padded-CSR
// slice in LDS (32KB), stream out coalesced.
__global__ __launch_bounds__(256) void k_binB(
    const unsigned int* __restrict__ bucketData, const int* __restrict__ cellcnt,
    int* __restrict__ colp, int* __restrict__ cnt) {
  __shared__ unsigned int slice[128 * 64];  // 32 KB
  __shared__ int lcnt[128];
  int b = blockIdx.x;
  for (int i = threadIdx.x; i < 128; i += TB) lcnt[i] = 0;
  __syncthreads();
  // thread tid owns cell (b, tid): count in cellcnt[tid*NBPAD+b]
  int c = cellcnt[threadIdx.x * NBPAD + b];
  if (c > CAPC) c = CAPC;
  const unsigned int* cell = bucketData + ((size_t)b * NBINA + threadIdx.x) * CAPC;
  for (int k = 0; k < c; ++k) {
    unsigned int rec = cell[k];
    int dl = rec >> 24;
    int pos = atomicAdd(&lcnt[dl], 1);
    if (pos < 64) slice[(dl << 6) + pos] = rec & 0xFFFFFFu;
  }
  __syncthreads();
  size_t obase = (size_t)b * (128 * 64);
  for (int i = threadIdx.x * 4; i < 128 * 64; i += TB * 4) {
    *(uint4*)(colp + obase + i) = *(const uint4*)(slice + i);
  }
  int node0 = b << 7;
  for (int i = threadIdx.x; i < 128; i += TB) cnt[node0 + i] = lcnt[i];
}

// ---- layer-2 transform: input h1 is bf16 -> A-fragments load directly.
__global__ __launch_bounds__(256) void k_xform_b16(
    const unsigned short* zin, const float* __restrict__ Wl,
    const float* __restrict__ Wr, const float* __restrict__ bl,
    unsigned short* __restrict__ y, unsigned short* zout, int n) {
  int lane = threadIdx.x & 63;
  int quad = lane >> 4, m = lane & 15;
  int w0 = (blockIdx.x * blockDim.x + threadIdx.x) >> 6;
  int nw = (gridDim.x * blockDim.x) >> 6;

  bf16x8 bfrag[8][2];
  float bias[4];
#pragma unroll
  for (int t = 0; t < 8; ++t) {
    const float* W = (t < 4) ? Wl : Wr;
    int row = (t & 3) * 16 + m;
#pragma unroll
    for (int s = 0; s < 2; ++s)
      bfrag[t][s] = ld_bf8(W + row * 64 + s * 32 + quad * 8);
  }
#pragma unroll
  for (int t = 0; t < 4; ++t) bias[t] = bl[t * 16 + m];

  int nT = (n + 15) >> 4;
  for (int tile = w0; tile < nT; tile += nw) {
    int node0 = tile << 4;
    int mrow = node0 + m;
    if (mrow >= n) mrow = n - 1;
    const unsigned short* xr = zin + (size_t)mrow * 64;
    bf16x8 a0 = *(const bf16x8*)(xr + quad * 8);
    bf16x8 a1 = *(const bf16x8*)(xr + 32 + quad * 8);

    f32x4 acc[8];
#pragma unroll
    for (int t = 0; t < 8; ++t) {
      f32x4 z4 = {0.f, 0.f, 0.f, 0.f};
      z4 = __builtin_amdgcn_mfma_f32_16x16x32_bf16(a0, bfrag[t][0], z4, 0, 0, 0);
      acc[t] = __builtin_amdgcn_mfma_f32_16x16x32_bf16(a1, bfrag[t][1], z4, 0, 0, 0);
    }

#pragma unroll
    for (int r = 0; r < 4; ++r) {
      int node = node0 + quad * 4 + r;
      if (node >= n) break;
      size_t rb = (size_t)node * 64 + m;
#pragma unroll
      for (int t = 0; t < 4; ++t) y[rb + t * 16] = bf16c(acc[t][r]);
#pragma unroll
      for (int t = 0; t < 4; ++t) zout[rb + t * 16] = bf16c(acc[t + 4][r] + bias[t]);
    }
  }
}

// ---- aggregate: z[node] = relu(mean_nbr(y) + z[node]); y,z bf16 rows (128B).
// 4 nodes/wave: 16-lane groups; sub picks row of a slot pair; 8 lanes x uint4
// = one full row. Slots 0..31 fully unrolled with per-slot predication
// (masked lanes issue no memory op). Rare slots 32..63 keep the dynamic path.
__global__ __launch_bounds__(256) void k_aggr(
    const unsigned short* __restrict__ yb, const int* __restrict__ cnt,
    const int* __restrict__ colp, unsigned short* zio, int n) {
  const unsigned int* y = (const unsigned int*)yb;  // 2 bf16 per u32; row = 32 u32
  int lane = threadIdx.x & 63;
  int wv = (blockIdx.x * blockDim.x + threadIdx.x) >> 6;
  int g16 = lane & 48;       // group base lane
  int lig = lane & 15;       // lane in group
  int sub = lig >> 3;        // which row of the current slot pair
  int fo = (lig & 7) * 4;    // u32 offset in row

  int node = (wv << 2) + (g16 >> 4);
  bool act = node < n;
  int cn = act ? node : 0;
  int deg = cnt[cn];
  int jcap = deg < 64 ? deg : 64;
  size_t crow = (size_t)cn << 6;
  int cidxA = colp[crow + lig];
  int cidxB = colp[crow + 16 + lig];

  int wmax = jcap;
  wmax = max(wmax, __shfl_xor(wmax, 16, 64));
  wmax = max(wmax, __shfl_xor(wmax, 32, 64));

  f32x2 acc[4];
#pragma unroll
  for (int k = 0; k < 4; ++k) acc[k] = (f32x2){0.f, 0.f};

#define ACCUM(U)                                             \
  do {                                                       \
    acc[0] += (f32x2){bflo((U).x), bfhi((U).x)};             \
    acc[1] += (f32x2){bflo((U).y), bfhi((U).y)};             \
    acc[2] += (f32x2){bflo((U).z), bfhi((U).z)};             \
    acc[3] += (f32x2){bflo((U).w), bfhi((U).w)};             \
  } while (0)

  // slots 0..15: full unroll, predicated loads (no BW cost for masked lanes)
#pragma unroll
  for (int s = 0; s < 16; s += 2) {
    int slot = s + sub;
    int c = __shfl(cidxA, g16 | slot, 64);
    if (slot < jcap) {
      uint4 v = *(const uint4*)(y + ((size_t)c << 5) + fo);
      ACCUM(v);
    }
  }
  if (wmax > 16) {  // slots 16..31: full unroll, predicated
#pragma unroll
    for (int s = 0; s < 16; s += 2) {
      int slot = s + sub;
      int c = __shfl(cidxB, g16 | slot, 64);
      if (slot + 16 < jcap) {
        uint4 v = *(const uint4*)(y + ((size_t)c << 5) + fo);
        ACCUM(v);
      }
    }
  }
  if (wmax > 32) {  // rare: slots 32..63
    int cidxC = colp[crow + 32 + lig];
    int cidxD = colp[crow + 48 + lig];
    {
      int lim = (wmax < 48 ? wmax : 48) - 32;
      for (int s = 0; s < lim; s += 2) {
        int slot = s + sub;
        int c = __shfl(cidxC, g16 | slot, 64);
        if (slot + 32 < jcap) {
          uint4 v = *(const uint4*)(y + ((size_t)c << 5) + fo);
          ACCUM(v);
        }
      }
    }
    if (wmax > 48) {
      int lim = wmax - 48;
      for (int s = 0; s < lim; s += 2) {
        int slot = s + sub;
        int c = __shfl(cidxD, g16 | slot, 64);
        if (slot + 48 < jcap) {
          uint4 v = *(const uint4*)(y + ((size_t)c << 5) + fo);
          ACCUM(v);
        }
      }
    }
  }
#undef ACCUM

#pragma unroll
  for (int k = 0; k < 4; ++k) {
    acc[k].x += __shfl_xor(acc[k].x, 8, 64);
    acc[k].y += __shfl_xor(acc[k].y, 8, 64);
  }

  if (act && sub == 0) {  // 8 lanes/group: lane owns u32s fo..fo+3 = feats 2fo..2fo+7
    float inv = (deg > 0) ? 1.0f / (float)deg : 0.f;
    unsigned int* zp = (unsigned int*)(zio + ((size_t)node << 6)) + fo;
    uint4 zv = *(uint4*)zp;
    zv.x = bfpk(fmaxf(fmaf(acc[0].x, inv, bflo(zv.x)), 0.f),
                fmaxf(fmaf(acc[0].y, inv, bfhi(zv.x)), 0.f));
    zv.y = bfpk(fmaxf(fmaf(acc[1].x, inv, bflo(zv.y)), 0.f),
                fmaxf(fmaf(acc[1].y, inv, bfhi(zv.y)), 0.f));
    zv.z = bfpk(fmaxf(fmaf(acc[2].x, inv, bflo(zv.z)), 0.f),
                fmaxf(fmaf(acc[2].y, inv, bfhi(zv.z)), 0.f));
    zv.w = bfpk(fmaxf(fmaf(acc[3].x, inv, bflo(zv.w)), 0.f),
                fmaxf(fmaf(acc[3].y, inv, bfhi(zv.w)), 0.f));
    *(uint4*)zp = zv;
  }
}

// ---- head: logits = h2(bf16) @ bf16(Wout)^T + bout; log_softmax -> fp32 out.
__global__ __launch_bounds__(256) void k_out(
    const unsigned short* __restrict__ h, const float* __restrict__ Wo,
    const float* __restrict__ bo, float* __restrict__ out, int n) {
  int lane = threadIdx.x & 63;
  int quad = lane >> 4, m = lane & 15;
  int w0 = (blockIdx.x * blockDim.x + threadIdx.x) >> 6;
  int nw = (gridDim.x * blockDim.x) >> 6;

  bf16x8 bfrag[4][2];
  float bias[4];
#pragma unroll
  for (int t = 0; t < 4; ++t) {
    int row = t * 16 + m;
#pragma unroll
    for (int s = 0; s < 2; ++s)
      bfrag[t][s] = ld_bf8(Wo + row * 64 + s * 32 + quad * 8);
    bias[t] = bo[t * 16 + m];
  }

  int nT = (n + 15) >> 4;
  for (int tile = w0; tile < nT; tile += nw) {
    int node0 = tile << 4;
    int mrow = node0 + m;
    if (mrow >= n) mrow = n - 1;
    const unsigned short* xr = h + (size_t)mrow * 64;
    bf16x8 a0 = *(const bf16x8*)(xr + quad * 8);
    bf16x8 a1 = *(const bf16x8*)(xr + 32 + quad * 8);

    f32x4 acc[4];
#pragma unroll
    for (int t = 0; t < 4; ++t) {
      f32x4 z4 = {0.f, 0.f, 0.f, 0.f};
      z4 = __builtin_amdgcn_mfma_f32_16x16x32_bf16(a0, bfrag[t][0], z4, 0, 0, 0);
      acc[t] = __builtin_amdgcn_mfma_f32_16x16x32_bf16(a1, bfrag[t][1], z4, 0, 0, 0);
    }

#pragma unroll
    for (int r = 0; r < 4; ++r) {
      int node = node0 + quad * 4 + r;
      if (node >= n) break;
      float l0 = acc[0][r] + bias[0];
      float l1 = acc[1][r] + bias[1];
      float l2 = acc[2][r] + bias[2];
      float l3 = acc[3][r] + bias[3];
      float mx = fmaxf(fmaxf(l0, l1), fmaxf(l2, l3));
#pragma unroll
      for (int off = 1; off <= 8; off <<= 1) mx = fmaxf(mx, __shfl_xor(mx, off, 64));
      float s = expf(l0 - mx) + expf(l1 - mx) + expf(l2 - mx) + expf(l3 - mx);
#pragma unroll
      for (int off = 1; off <= 8; off <<= 1) s += __shfl_xor(s, off, 64);
      float ls = logf(s);
      size_t rb = (size_t)node * 64 + m;
      out[rb + 0]  = l0 - mx - ls;
      out[rb + 16] = l1 - mx - ls;
      out[rb + 32] = l2 - mx - ls;
      out[rb + 48] = l3 - mx - ls;
    }
  }
}

extern "C" void kernel_launch(void* const* d_in, const int* in_sizes, int n_in,
                              void* d_out, int out_size, void* d_ws, size_t ws_size,
                              hipStream_t stream) {
  const float* x    = (const float*)d_in[0];
  const int*   ei   = (const int*)d_in[1];
  const float* W1l  = (const float*)d_in[2];
  const float* b1l  = (const float*)d_in[3];
  const float* W1r  = (const float*)d_in[4];
  const float* W2l  = (const float*)d_in[5];
  const float* b2l  = (const float*)d_in[6];
  const float* W2r  = (const float*)d_in[7];
  const float* Wout = (const float*)d_in[8];
  const float* bout = (const float*)d_in[9];
  int N = in_sizes[0] / 64;
  int E = in_sizes[1] / 2;
  int NB = (N + 127) >> 7;  // 128-node buckets; NB=782 <= NBPAD

  char* p = (char*)d_ws;
  auto carve = [&](size_t bytes) {
    char* r = p;
    p += (bytes + 255) & ~(size_t)255;
    return r;
  };
  int* cellcnt       = (int*)carve((size_t)NBINA * NBPAD * 4);   // 1 MB
  int* cnt           = (int*)carve((size_t)NB * 128 * 4);        // padded
  int* colp          = (int*)carve((size_t)NB * 128 * 64 * 4);   // padded
  unsigned short* y  = (unsigned short*)carve((size_t)N * 64 * 2);
  unsigned short* z  = (unsigned short*)carve((size_t)N * 64 * 2);
  unsigned int* bucketData = (unsigned int*)carve((size_t)NB * NBINA * CAPC * 4);  // 25.6 MB

  int aggr_blocks = (N + 15) / 16;  // 4 nodes/wave, 4 waves/block
  // single-pass binning || layer-1 transform (one fused 1024-thread launch)
  k_binA_xf<<<NBINA + XFB, TBF, 0, stream>>>(ei, E, cellcnt, bucketData, NB,
                                             x, W1l, W1r, b1l, y, z, N);
  k_binB<<<NB, TB, 0, stream>>>(bucketData, cellcnt, colp, cnt);
  k_aggr<<<aggr_blocks, TB, 0, stream>>>(y, cnt, colp, z, N);  // z = h1 (bf16)
  // layer 2 (reads z in place; y buffer reused)
  k_xform_b16<<<XFB, TB, 0, stream>>>(z, W2l, W2r, b2l, y, z, N);
  k_aggr<<<aggr_blocks, TB, 0, stream>>>(y, cnt, colp, z, N);  // z = h2 (bf16)
  // head
  k_out<<<XFB, TB, 0, stream>>>(z, Wout, bout, (float*)d_out, N);
}

// Round 6
// 242.200 us; speedup vs baseline: 1.0639x; 1.0639x over previous
//
#include <hip/hip_runtime.h>

// GraphSAGE encoder: N=100000, E=1600000, D=64. fp32 in/out, bf16 internal.
// relu(Wl@mean(x) + Wr@x + b) == relu(mean(Wl@x) + (Wr@x + b))  [linearity]
// Round-15: round-14's 1024-thr fused kernel spilled the MFMA path (VGPR
// capped 88->64, +10MB spill traffic, no gain). De-fused along resource
// lines: bin path gets its own 1024-thr register-light kernel (16 waves/CU,
// single-pass cells -> half the memory work of the old 38us two-pass binA);
// xform1 (88 VGPR, 256-thr) is instead fused behind binB (LDS-heavy,
// register-light, 782 short blocks -> no occupancy tail; xform blocks
// backfill as binB drains).
//   k_binA     : 1024-thr single-pass edge binning into per-(bucket,block)
//                cells (block-local LDS counters, zero global atomics)
//   k_binB_xf  : [blocks 0..NB)  per-bucket padded-CSR slice in LDS (32KB)
//                [blocks NB..)   y1||z1 = bf16(x) @ bf16([W1l;W1r])^T
//   k_aggr     : h = relu(mean_nbr(y) + z) in-place on z, all bf16 rows
//   k_xform_b16: y2||z2 = h1 @ bf16([W2l;W2r])^T (in-place z)
//   k_out      : logits = h2 @ Wout^T + bout; log_softmax -> d_out (fp32)

#define TB 256
#define TBA 1024   // k_binA block size (16 waves, register-light)
#define NBINA 256  // bin blocks (== TB so binB can go thread-per-cell)
#define XFB 512    // xform blocks appended to k_binB_xf
#define CAPC 32    // slots per (bucket,block) cell: mean 8, P(>32)~1e-12
#define NBPAD 1024

typedef __attribute__((ext_vector_type(8))) short bf16x8;
typedef __attribute__((ext_vector_type(4))) float f32x4;
typedef __attribute__((ext_vector_type(2))) float f32x2;

__device__ __forceinline__ unsigned short bf16c(float f) {
  union { float f; unsigned u; } v; v.f = f;
  unsigned r = (v.u + 0x7FFFu + ((v.u >> 16) & 1u)) >> 16;  // RNE
  return (unsigned short)r;
}

__device__ __forceinline__ bf16x8 ld_bf8(const float* p) {
  float4 a = *(const float4*)p;
  float4 b = *(const float4*)(p + 4);
  bf16x8 r;
  r[0] = bf16c(a.x); r[1] = bf16c(a.y); r[2] = bf16c(a.z); r[3] = bf16c(a.w);
  r[4] = bf16c(b.x); r[5] = bf16c(b.y); r[6] = bf16c(b.z); r[7] = bf16c(b.w);
  return r;
}

__device__ __forceinline__ float bflo(unsigned u) { return __uint_as_float(u << 16); }
__device__ __forceinline__ float bfhi(unsigned u) { return __uint_as_float(u & 0xFFFF0000u); }
__device__ __forceinline__ unsigned bfpk(float lo, float hi) {
  return (unsigned)bf16c(lo) | ((unsigned)bf16c(hi) << 16);
}

// ---- single-pass binning: block bb owns cell (b,bb) = 32 slots; placement
// via block-local LDS counter. One pass over edges, no global atomics.
__global__ __launch_bounds__(1024) void k_binA(
    const int* __restrict__ ei, int E,
    int* __restrict__ cellcnt, unsigned int* __restrict__ bucketData, int NB) {
  __shared__ int lcnt[NBPAD];
  __shared__ int s_nz;
  if (threadIdx.x == 0) s_nz = 0;
  for (int i = threadIdx.x; i < NBPAD; i += TBA) lcnt[i] = 0;
  __syncthreads();
  int nz = 0;
  for (int i = threadIdx.x; i < 2048; i += TBA) nz |= ei[2 * i + 1];
  if (nz) atomicOr(&s_nz, 1);
  __syncthreads();
  bool m64 = (s_nz == 0);  // int64 layout
  int bb = blockIdx.x;

  long long e0 = (long long)E * bb / NBINA;
  long long e1 = (long long)E * (bb + 1) / NBINA;
  for (long long e = e0 + threadIdx.x; e < e1; e += TBA) {
    int src, dst;
    if (m64) {
      src = ((const int2*)ei)[e].x;
      dst = ((const int2*)ei)[(long long)E + e].x;
    } else {
      src = ei[e];
      dst = ei[(long long)E + e];
    }
    int b = dst >> 7;
    int pos = atomicAdd(&lcnt[b], 1);
    if (pos < CAPC)
      bucketData[((size_t)b * NBINA + bb) * CAPC + pos] =
          ((unsigned)(dst & 127) << 24) | (unsigned)src;
  }
  __syncthreads();
  // coalesced: block bb owns contiguous row cellcnt[bb*NBPAD + 0..NB)
  for (int b = threadIdx.x; b < NB; b += TBA) cellcnt[bb * NBPAD + b] = lcnt[b];
}

// ---- fused: binB (blocks < NB) || layer-1 transform (the rest).
// binB: drain cells thread-per-cell into the bucket's padded-CSR slice in
// LDS, stream out coalesced. xform: register-heavy MFMA path, no LDS use.
__global__ __launch_bounds__(256) void k_binB_xf(
    const unsigned int* __restrict__ bucketData, const int* __restrict__ cellcnt,
    int* __restrict__ colp, int* __restrict__ cnt, int NB,
    const float* __restrict__ xin, const float* __restrict__ Wl,
    const float* __restrict__ Wr, const float* __restrict__ bl,
    unsigned short* __restrict__ y, unsigned short* __restrict__ zout, int n) {
  if (blockIdx.x < (unsigned)NB) {
    __shared__ unsigned int slice[128 * 64];  // 32 KB
    __shared__ int lcnt[128];
    int b = blockIdx.x;
    for (int i = threadIdx.x; i < 128; i += TB) lcnt[i] = 0;
    __syncthreads();
    // thread tid owns cell (b, tid): count in cellcnt[tid*NBPAD+b]
    int c = cellcnt[threadIdx.x * NBPAD + b];
    if (c > CAPC) c = CAPC;
    const unsigned int* cell = bucketData + ((size_t)b * NBINA + threadIdx.x) * CAPC;
    for (int k = 0; k < c; ++k) {
      unsigned int rec = cell[k];
      int dl = rec >> 24;
      int pos = atomicAdd(&lcnt[dl], 1);
      if (pos < 64) slice[(dl << 6) + pos] = rec & 0xFFFFFFu;
    }
    __syncthreads();
    size_t obase = (size_t)b * (128 * 64);
    for (int i = threadIdx.x * 4; i < 128 * 64; i += TB * 4) {
      *(uint4*)(colp + obase + i) = *(const uint4*)(slice + i);
    }
    int node0 = b << 7;
    for (int i = threadIdx.x; i < 128; i += TB) cnt[node0 + i] = lcnt[i];
    return;
  }

  // ---- layer-1 transform: y||z = bf16(x fp32) @ bf16([Wl;Wr])^T; y,z bf16.
  // Wave = 16-node tile, grid-stride. D layout (m89): feat=lane&15, node=quad*4+reg.
  int lane = threadIdx.x & 63;
  int quad = lane >> 4, m = lane & 15;
  int w0 = ((blockIdx.x - NB) * TB + threadIdx.x) >> 6;
  int nw = (XFB * TB) >> 6;

  bf16x8 bfrag[8][2];
  float bias[4];
#pragma unroll
  for (int t = 0; t < 8; ++t) {
    const float* W = (t < 4) ? Wl : Wr;
    int row = (t & 3) * 16 + m;
#pragma unroll
    for (int s = 0; s < 2; ++s)
      bfrag[t][s] = ld_bf8(W + row * 64 + s * 32 + quad * 8);
  }
#pragma unroll
  for (int t = 0; t < 4; ++t) bias[t] = bl[t * 16 + m];

  int nT = (n + 15) >> 4;
  for (int tile = w0; tile < nT; tile += nw) {
    int node0 = tile << 4;
    int mrow = node0 + m;
    if (mrow >= n) mrow = n - 1;
    const float* xr = xin + (size_t)mrow * 64;
    bf16x8 a0 = ld_bf8(xr + quad * 8);
    bf16x8 a1 = ld_bf8(xr + 32 + quad * 8);

    f32x4 acc[8];
#pragma unroll
    for (int t = 0; t < 8; ++t) {
      f32x4 z4 = {0.f, 0.f, 0.f, 0.f};
      z4 = __builtin_amdgcn_mfma_f32_16x16x32_bf16(a0, bfrag[t][0], z4, 0, 0, 0);
      acc[t] = __builtin_amdgcn_mfma_f32_16x16x32_bf16(a1, bfrag[t][1], z4, 0, 0, 0);
    }

#pragma unroll
    for (int r = 0; r < 4; ++r) {
      int node = node0 + quad * 4 + r;
      if (node >= n) break;
      size_t rb = (size_t)node * 64 + m;
#pragma unroll
      for (int t = 0; t < 4; ++t) y[rb + t * 16] = bf16c(acc[t][r]);
#pragma unroll
      for (int t = 0; t < 4; ++t) zout[rb + t * 16] = bf16c(acc[t + 4][r] + bias[t]);
    }
  }
}

// ---- layer-2 transform: input h1 is bf16 -> A-fragments load directly.
__global__ __launch_bounds__(256) void k_xform_b16(
    const unsigned short* zin, const float* __restrict__ Wl,
    const float* __restrict__ Wr, const float* __restrict__ bl,
    unsigned short* __restrict__ y, unsigned short* zout, int n) {
  int lane = threadIdx.x & 63;
  int quad = lane >> 4, m = lane & 15;
  int w0 = (blockIdx.x * blockDim.x + threadIdx.x) >> 6;
  int nw = (gridDim.x * blockDim.x) >> 6;

  bf16x8 bfrag[8][2];
  float bias[4];
#pragma unroll
  for (int t = 0; t < 8; ++t) {
    const float* W = (t < 4) ? Wl : Wr;
    int row = (t & 3) * 16 + m;
#pragma unroll
    for (int s = 0; s < 2; ++s)
      bfrag[t][s] = ld_bf8(W + row * 64 + s * 32 + quad * 8);
  }
#pragma unroll
  for (int t = 0; t < 4; ++t) bias[t] = bl[t * 16 + m];

  int nT = (n + 15) >> 4;
  for (int tile = w0; tile < nT; tile += nw) {
    int node0 = tile << 4;
    int mrow = node0 + m;
    if (mrow >= n) mrow = n - 1;
    const unsigned short* xr = zin + (size_t)mrow * 64;
    bf16x8 a0 = *(const bf16x8*)(xr + quad * 8);
    bf16x8 a1 = *(const bf16x8*)(xr + 32 + quad * 8);

    f32x4 acc[8];
#pragma unroll
    for (int t = 0; t < 8; ++t) {
      f32x4 z4 = {0.f, 0.f, 0.f, 0.f};
      z4 = __builtin_amdgcn_mfma_f32_16x16x32_bf16(a0, bfrag[t][0], z4, 0, 0, 0);
      acc[t] = __builtin_amdgcn_mfma_f32_16x16x32_bf16(a1, bfrag[t][1], z4, 0, 0, 0);
    }

#pragma unroll
    for (int r = 0; r < 4; ++r) {
      int node = node0 + quad * 4 + r;
      if (node >= n) break;
      size_t rb = (size_t)node * 64 + m;
#pragma unroll
      for (int t = 0; t < 4; ++t) y[rb + t * 16] = bf16c(acc[t][r]);
#pragma unroll
      for (int t = 0; t < 4; ++t) zout[rb + t * 16] = bf16c(acc[t + 4][r] + bias[t]);
    }
  }
}

// ---- aggregate: z[node] = relu(mean_nbr(y) + z[node]); y,z bf16 rows (128B).
// 4 nodes/wave: 16-lane groups; sub picks row of a slot pair; 8 lanes x uint4
// = one full row. Slots 0..31 fully unrolled with per-slot predication
// (masked lanes issue no memory op). Rare slots 32..63 keep the dynamic path.
__global__ __launch_bounds__(256) void k_aggr(
    const unsigned short* __restrict__ yb, const int* __restrict__ cnt,
    const int* __restrict__ colp, unsigned short* zio, int n) {
  const unsigned int* y = (const unsigned int*)yb;  // 2 bf16 per u32; row = 32 u32
  int lane = threadIdx.x & 63;
  int wv = (blockIdx.x * blockDim.x + threadIdx.x) >> 6;
  int g16 = lane & 48;       // group base lane
  int lig = lane & 15;       // lane in group
  int sub = lig >> 3;        // which row of the current slot pair
  int fo = (lig & 7) * 4;    // u32 offset in row

  int node = (wv << 2) + (g16 >> 4);
  bool act = node < n;
  int cn = act ? node : 0;
  int deg = cnt[cn];
  int jcap = deg < 64 ? deg : 64;
  size_t crow = (size_t)cn << 6;
  int cidxA = colp[crow + lig];
  int cidxB = colp[crow + 16 + lig];

  int wmax = jcap;
  wmax = max(wmax, __shfl_xor(wmax, 16, 64));
  wmax = max(wmax, __shfl_xor(wmax, 32, 64));

  f32x2 acc[4];
#pragma unroll
  for (int k = 0; k < 4; ++k) acc[k] = (f32x2){0.f, 0.f};

#define ACCUM(U)                                             \
  do {                                                       \
    acc[0] += (f32x2){bflo((U).x), bfhi((U).x)};             \
    acc[1] += (f32x2){bflo((U).y), bfhi((U).y)};             \
    acc[2] += (f32x2){bflo((U).z), bfhi((U).z)};             \
    acc[3] += (f32x2){bflo((U).w), bfhi((U).w)};             \
  } while (0)

  // slots 0..15: full unroll, predicated loads (no BW cost for masked lanes)
#pragma unroll
  for (int s = 0; s < 16; s += 2) {
    int slot = s + sub;
    int c = __shfl(cidxA, g16 | slot, 64);
    if (slot < jcap) {
      uint4 v = *(const uint4*)(y + ((size_t)c << 5) + fo);
      ACCUM(v);
    }
  }
  if (wmax > 16) {  // slots 16..31: full unroll, predicated
#pragma unroll
    for (int s = 0; s < 16; s += 2) {
      int slot = s + sub;
      int c = __shfl(cidxB, g16 | slot, 64);
      if (slot + 16 < jcap) {
        uint4 v = *(const uint4*)(y + ((size_t)c << 5) + fo);
        ACCUM(v);
      }
    }
  }
  if (wmax > 32) {  // rare: slots 32..63
    int cidxC = colp[crow + 32 + lig];
    int cidxD = colp[crow + 48 + lig];
    {
      int lim = (wmax < 48 ? wmax : 48) - 32;
      for (int s = 0; s < lim; s += 2) {
        int slot = s + sub;
        int c = __shfl(cidxC, g16 | slot, 64);
        if (slot + 32 < jcap) {
          uint4 v = *(const uint4*)(y + ((size_t)c << 5) + fo);
          ACCUM(v);
        }
      }
    }
    if (wmax > 48) {
      int lim = wmax - 48;
      for (int s = 0; s < lim; s += 2) {
        int slot = s + sub;
        int c = __shfl(cidxD, g16 | slot, 64);
        if (slot + 48 < jcap) {
          uint4 v = *(const uint4*)(y + ((size_t)c << 5) + fo);
          ACCUM(v);
        }
      }
    }
  }
#undef ACCUM

#pragma unroll
  for (int k = 0; k < 4; ++k) {
    acc[k].x += __shfl_xor(acc[k].x, 8, 64);
    acc[k].y += __shfl_xor(acc[k].y, 8, 64);
  }

  if (act && sub == 0) {  // 8 lanes/group: lane owns u32s fo..fo+3 = feats 2fo..2fo+7
    float inv = (deg > 0) ? 1.0f / (float)deg : 0.f;
    unsigned int* zp = (unsigned int*)(zio + ((size_t)node << 6)) + fo;
    uint4 zv = *(uint4*)zp;
    zv.x = bfpk(fmaxf(fmaf(acc[0].x, inv, bflo(zv.x)), 0.f),
                fmaxf(fmaf(acc[0].y, inv, bfhi(zv.x)), 0.f));
    zv.y = bfpk(fmaxf(fmaf(acc[1].x, inv, bflo(zv.y)), 0.f),
                fmaxf(fmaf(acc[1].y, inv, bfhi(zv.y)), 0.f));
    zv.z = bfpk(fmaxf(fmaf(acc[2].x, inv, bflo(zv.z)), 0.f),
                fmaxf(fmaf(acc[2].y, inv, bfhi(zv.z)), 0.f));
    zv.w = bfpk(fmaxf(fmaf(acc[3].x, inv, bflo(zv.w)), 0.f),
                fmaxf(fmaf(acc[3].y, inv, bfhi(zv.w)), 0.f));
    *(uint4*)zp = zv;
  }
}

// ---- head: logits = h2(bf16) @ bf16(Wout)^T + bout; log_softmax -> fp32 out.
__global__ __launch_bounds__(256) void k_out(
    const unsigned short* __restrict__ h, const float* __restrict__ Wo,
    const float* __restrict__ bo, float* __restrict__ out, int n) {
  int lane = threadIdx.x & 63;
  int quad = lane >> 4, m = lane & 15;
  int w0 = (blockIdx.x * blockDim.x + threadIdx.x) >> 6;
  int nw = (gridDim.x * blockDim.x) >> 6;

  bf16x8 bfrag[4][2];
  float bias[4];
#pragma unroll
  for (int t = 0; t < 4; ++t) {
    int row = t * 16 + m;
#pragma unroll
    for (int s = 0; s < 2; ++s)
      bfrag[t][s] = ld_bf8(Wo + row * 64 + s * 32 + quad * 8);
    bias[t] = bo[t * 16 + m];
  }

  int nT = (n + 15) >> 4;
  for (int tile = w0; tile < nT; tile += nw) {
    int node0 = tile << 4;
    int mrow = node0 + m;
    if (mrow >= n) mrow = n - 1;
    const unsigned short* xr = h + (size_t)mrow * 64;
    bf16x8 a0 = *(const bf16x8*)(xr + quad * 8);
    bf16x8 a1 = *(const bf16x8*)(xr + 32 + quad * 8);

    f32x4 acc[4];
#pragma unroll
    for (int t = 0; t < 4; ++t) {
      f32x4 z4 = {0.f, 0.f, 0.f, 0.f};
      z4 = __builtin_amdgcn_mfma_f32_16x16x32_bf16(a0, bfrag[t][0], z4, 0, 0, 0);
      acc[t] = __builtin_amdgcn_mfma_f32_16x16x32_bf16(a1, bfrag[t][1], z4, 0, 0, 0);
    }

#pragma unroll
    for (int r = 0; r < 4; ++r) {
      int node = node0 + quad * 4 + r;
      if (node >= n) break;
      float l0 = acc[0][r] + bias[0];
      float l1 = acc[1][r] + bias[1];
      float l2 = acc[2][r] + bias[2];
      float l3 = acc[3][r] + bias[3];
      float mx = fmaxf(fmaxf(l0, l1), fmaxf(l2, l3));
#pragma unroll
      for (int off = 1; off <= 8; off <<= 1) mx = fmaxf(mx, __shfl_xor(mx, off, 64));
      float s = expf(l0 - mx) + expf(l1 - mx) + expf(l2 - mx) + expf(l3 - mx);
#pragma unroll
      for (int off = 1; off <= 8; off <<= 1) s += __shfl_xor(s, off, 64);
      float ls = logf(s);
      size_t rb = (size_t)node * 64 + m;
      out[rb + 0]  = l0 - mx - ls;
      out[rb + 16] = l1 - mx - ls;
      out[rb + 32] = l2 - mx - ls;
      out[rb + 48] = l3 - mx - ls;
    }
  }
}

extern "C" void kernel_launch(void* const* d_in, const int* in_sizes, int n_in,
                              void* d_out, int out_size, void* d_ws, size_t ws_size,
                              hipStream_t stream) {
  const float* x    = (const float*)d_in[0];
  const int*   ei   = (const int*)d_in[1];
  const float* W1l  = (const float*)d_in[2];
  const float* b1l  = (const float*)d_in[3];
  const float* W1r  = (const float*)d_in[4];
  const float* W2l  = (const float*)d_in[5];
  const float* b2l  = (const float*)d_in[6];
  const float* W2r  = (const float*)d_in[7];
  const float* Wout = (const float*)d_in[8];
  const float* bout = (const float*)d_in[9];
  int N = in_sizes[0] / 64;
  int E = in_sizes[1] / 2;
  int NB = (N + 127) >> 7;  // 128-node buckets; NB=782 <= NBPAD

  char* p = (char*)d_ws;
  auto carve = [&](size_t bytes) {
    char* r = p;
    p += (bytes + 255) & ~(size_t)255;
    return r;
  };
  int* cellcnt       = (int*)carve((size_t)NBINA * NBPAD * 4);   // 1 MB
  int* cnt           = (int*)carve((size_t)NB * 128 * 4);        // padded
  int* colp          = (int*)carve((size_t)NB * 128 * 64 * 4);   // padded
  unsigned short* y  = (unsigned short*)carve((size_t)N * 64 * 2);
  unsigned short* z  = (unsigned short*)carve((size_t)N * 64 * 2);
  unsigned int* bucketData = (unsigned int*)carve((size_t)NB * NBINA * CAPC * 4);  // 25.6 MB

  int aggr_blocks = (N + 15) / 16;  // 4 nodes/wave, 4 waves/block
  // single-pass binning (1024-thr, register-light, 16 waves/CU)
  k_binA<<<NBINA, TBA, 0, stream>>>(ei, E, cellcnt, bucketData, NB);
  // binB || layer-1 transform (256-thr; binB blocks first, xform backfills)
  k_binB_xf<<<NB + XFB, TB, 0, stream>>>(bucketData, cellcnt, colp, cnt, NB,
                                         x, W1l, W1r, b1l, y, z, N);
  k_aggr<<<aggr_blocks, TB, 0, stream>>>(y, cnt, colp, z, N);  // z = h1 (bf16)
  // layer 2 (reads z in place; y buffer reused)
  k_xform_b16<<<XFB, TB, 0, stream>>>(z, W2l, W2r, b2l, y, z, N);
  k_aggr<<<aggr_blocks, TB, 0, stream>>>(y, cnt, colp, z, N);  // z = h2 (bf16)
  // head
  k_out<<<XFB, TB, 0, stream>>>(z, Wout, bout, (float*)d_out, N);
}

// Round 8
// 236.307 us; speedup vs baseline: 1.0905x; 1.0249x over previous
//
#include <hip/hip_runtime.h>

// GraphSAGE encoder: N=100000, E=1600000, D=64. fp32 in/out, bf16 internal.
// relu(Wl@mean(x) + Wr@x + b) == relu(mean(Wl@x) + (Wr@x + b))  [linearity]
// Round-17: resubmit of round-16 (bench infra failed twice; no profile).
// All fusion attempts were neutral-to-negative (r14: VGPR spill; r15:
// binB_xf 41.5us > binB 15 + xform 18 separate -- 33KB LDS reserved for ALL
// blocks incl. LDS-free xform blocks -> Occ 13.9%). De-fused to best shapes:
//   k_binA     : 1024-thr single-pass edge binning into per-(bucket,block)
//                cells (block-local LDS counters, zero global atomics)
//   k_binB     : separate; uint4 cell drain (4x fewer loads); slice padded
//                to stride-68 (bank = (node*4+pos)%32 -> uniform, kills the
//                pos-dominated conflicts; 16B-aligned stream-out kept)
//   k_xform_f32: y1||z1 = bf16(x) @ bf16([W1l;W1r])^T (88 VGPR, no LDS)
//   k_aggr     : h = relu(mean_nbr(y) + z) in-place on z, all bf16 rows
//   k_xform_b16: y2||z2 = h1 @ bf16([W2l;W2r])^T (in-place z)
//   k_out      : logits = h2 @ Wout^T + bout; log_softmax -> d_out (fp32)

#define TB 256
#define TBA 1024   // k_binA block size (16 waves, register-light)
#define NBINA 256  // bin blocks (== TB so binB can go thread-per-cell)
#define XFB 512    // xform grid
#define CAPC 32    // slots per (bucket,block) cell: mean 8, P(>32)~1e-12
#define NBPAD 1024
#define SP 68      // padded slice stride (u32): 68%32=4, 68*4B 16B-aligned

typedef __attribute__((ext_vector_type(8))) short bf16x8;
typedef __attribute__((ext_vector_type(4))) float f32x4;
typedef __attribute__((ext_vector_type(2))) float f32x2;

__device__ __forceinline__ unsigned short bf16c(float f) {
  union { float f; unsigned u; } v; v.f = f;
  unsigned r = (v.u + 0x7FFFu + ((v.u >> 16) & 1u)) >> 16;  // RNE
  return (unsigned short)r;
}

__device__ __forceinline__ bf16x8 ld_bf8(const float* p) {
  float4 a = *(const float4*)p;
  float4 b = *(const float4*)(p + 4);
  bf16x8 r;
  r[0] = bf16c(a.x); r[1] = bf16c(a.y); r[2] = bf16c(a.z); r[3] = bf16c(a.w);
  r[4] = bf16c(b.x); r[5] = bf16c(b.y); r[6] = bf16c(b.z); r[7] = bf16c(b.w);
  return r;
}

__device__ __forceinline__ float bflo(unsigned u) { return __uint_as_float(u << 16); }
__device__ __forceinline__ float bfhi(unsigned u) { return __uint_as_float(u & 0xFFFF0000u); }
__device__ __forceinline__ unsigned bfpk(float lo, float hi) {
  return (unsigned)bf16c(lo) | ((unsigned)bf16c(hi) << 16);
}

// ---- single-pass binning: block bb owns cell (b,bb) = 32 slots; placement
// via block-local LDS counter. One pass over edges, no global atomics.
__global__ __launch_bounds__(1024) void k_binA(
    const int* __restrict__ ei, int E,
    int* __restrict__ cellcnt, unsigned int* __restrict__ bucketData, int NB) {
  __shared__ int lcnt[NBPAD];
  __shared__ int s_nz;
  if (threadIdx.x == 0) s_nz = 0;
  for (int i = threadIdx.x; i < NBPAD; i += TBA) lcnt[i] = 0;
  __syncthreads();
  int nz = 0;
  for (int i = threadIdx.x; i < 2048; i += TBA) nz |= ei[2 * i + 1];
  if (nz) atomicOr(&s_nz, 1);
  __syncthreads();
  bool m64 = (s_nz == 0);  // int64 layout
  int bb = blockIdx.x;

  long long e0 = (long long)E * bb / NBINA;
  long long e1 = (long long)E * (bb + 1) / NBINA;
  for (long long e = e0 + threadIdx.x; e < e1; e += TBA) {
    int src, dst;
    if (m64) {
      src = ((const int2*)ei)[e].x;
      dst = ((const int2*)ei)[(long long)E + e].x;
    } else {
      src = ei[e];
      dst = ei[(long long)E + e];
    }
    int b = dst >> 7;
    int pos = atomicAdd(&lcnt[b], 1);
    if (pos < CAPC)
      bucketData[((size_t)b * NBINA + bb) * CAPC + pos] =
          ((unsigned)(dst & 127) << 24) | (unsigned)src;
  }
  __syncthreads();
  // coalesced: block bb owns contiguous row cellcnt[bb*NBPAD + 0..NB)
  for (int b = threadIdx.x; b < NB; b += TBA) cellcnt[bb * NBPAD + b] = lcnt[b];
}

// ---- phase B: drain cells (uint4-vectorized, thread-per-cell) into the
// bucket's padded-CSR slice in LDS, stream out coalesced.
__global__ __launch_bounds__(256) void k_binB(
    const unsigned int* __restrict__ bucketData, const int* __restrict__ cellcnt,
    int* __restrict__ colp, int* __restrict__ cnt) {
  __shared__ unsigned int slice[128 * SP];  // 34 KB, stride-68 padded
  __shared__ int lcnt[128];
  int b = blockIdx.x;
  for (int i = threadIdx.x; i < 128; i += TB) lcnt[i] = 0;
  __syncthreads();
  // thread tid owns cell (b, tid): count in cellcnt[tid*NBPAD+b]
  int c = cellcnt[threadIdx.x * NBPAD + b];
  if (c > CAPC) c = CAPC;
  const uint4* cell4 =
      (const uint4*)(bucketData + ((size_t)b * NBINA + threadIdx.x) * CAPC);
#pragma unroll
  for (int k4 = 0; k4 < CAPC / 4; ++k4) {
    if (k4 * 4 >= c) break;
    uint4 r4 = cell4[k4];
#pragma unroll
    for (int j = 0; j < 4; ++j) {
      int k = k4 * 4 + j;
      if (k < c) {
        unsigned rec = (&r4.x)[j];
        int dl = rec >> 24;
        int pos = atomicAdd(&lcnt[dl], 1);
        if (pos < 64) slice[dl * SP + pos] = rec & 0xFFFFFFu;
      }
    }
  }
  __syncthreads();
  size_t obase = (size_t)b * (128 * 64);
  for (int i = threadIdx.x * 4; i < 128 * 64; i += TB * 4) {
    int node = i >> 6, j = i & 63;
    *(uint4*)(colp + obase + i) = *(const uint4*)(slice + node * SP + j);
  }
  int node0 = b << 7;
  for (int i = threadIdx.x; i < 128; i += TB) cnt[node0 + i] = lcnt[i];
}

// ---- layer-1 transform: y||z = bf16(x fp32) @ bf16([Wl;Wr])^T; y,z bf16.
// Wave = 16-node tile, grid-stride. D layout (m89): feat=lane&15, node=quad*4+reg.
__global__ __launch_bounds__(256) void k_xform_f32(
    const float* __restrict__ xin, const float* __restrict__ Wl,
    const float* __restrict__ Wr, const float* __restrict__ bl,
    unsigned short* __restrict__ y, unsigned short* __restrict__ zout, int n) {
  int lane = threadIdx.x & 63;
  int quad = lane >> 4, m = lane & 15;
  int w0 = (blockIdx.x * blockDim.x + threadIdx.x) >> 6;
  int nw = (gridDim.x * blockDim.x) >> 6;

  bf16x8 bfrag[8][2];
  float bias[4];
#pragma unroll
  for (int t = 0; t < 8; ++t) {
    const float* W = (t < 4) ? Wl : Wr;
    int row = (t & 3) * 16 + m;
#pragma unroll
    for (int s = 0; s < 2; ++s)
      bfrag[t][s] = ld_bf8(W + row * 64 + s * 32 + quad * 8);
  }
#pragma unroll
  for (int t = 0; t < 4; ++t) bias[t] = bl[t * 16 + m];

  int nT = (n + 15) >> 4;
  for (int tile = w0; tile < nT; tile += nw) {
    int node0 = tile << 4;
    int mrow = node0 + m;
    if (mrow >= n) mrow = n - 1;
    const float* xr = xin + (size_t)mrow * 64;
    bf16x8 a0 = ld_bf8(xr + quad * 8);
    bf16x8 a1 = ld_bf8(xr + 32 + quad * 8);

    f32x4 acc[8];
#pragma unroll
    for (int t = 0; t < 8; ++t) {
      f32x4 z4 = {0.f, 0.f, 0.f, 0.f};
      z4 = __builtin_amdgcn_mfma_f32_16x16x32_bf16(a0, bfrag[t][0], z4, 0, 0, 0);
      acc[t] = __builtin_amdgcn_mfma_f32_16x16x32_bf16(a1, bfrag[t][1], z4, 0, 0, 0);
    }

#pragma unroll
    for (int r = 0; r < 4; ++r) {
      int node = node0 + quad * 4 + r;
      if (node >= n) break;
      size_t rb = (size_t)node * 64 + m;
#pragma unroll
      for (int t = 0; t < 4; ++t) y[rb + t * 16] = bf16c(acc[t][r]);
#pragma unroll
      for (int t = 0; t < 4; ++t) zout[rb + t * 16] = bf16c(acc[t + 4][r] + bias[t]);
    }
  }
}

// ---- layer-2 transform: input h1 is bf16 -> A-fragments load directly.
__global__ __launch_bounds__(256) void k_xform_b16(
    const unsigned short* zin, const float* __restrict__ Wl,
    const float* __restrict__ Wr, const float* __restrict__ bl,
    unsigned short* __restrict__ y, unsigned short* zout, int n) {
  int lane = threadIdx.x & 63;
  int quad = lane >> 4, m = lane & 15;
  int w0 = (blockIdx.x * blockDim.x + threadIdx.x) >> 6;
  int nw = (gridDim.x * blockDim.x) >> 6;

  bf16x8 bfrag[8][2];
  float bias[4];
#pragma unroll
  for (int t = 0; t < 8; ++t) {
    const float* W = (t < 4) ? Wl : Wr;
    int row = (t & 3) * 16 + m;
#pragma unroll
    for (int s = 0; s < 2; ++s)
      bfrag[t][s] = ld_bf8(W + row * 64 + s * 32 + quad * 8);
  }
#pragma unroll
  for (int t = 0; t < 4; ++t) bias[t] = bl[t * 16 + m];

  int nT = (n + 15) >> 4;
  for (int tile = w0; tile < nT; tile += nw) {
    int node0 = tile << 4;
    int mrow = node0 + m;
    if (mrow >= n) mrow = n - 1;
    const unsigned short* xr = zin + (size_t)mrow * 64;
    bf16x8 a0 = *(const bf16x8*)(xr + quad * 8);
    bf16x8 a1 = *(const bf16x8*)(xr + 32 + quad * 8);

    f32x4 acc[8];
#pragma unroll
    for (int t = 0; t < 8; ++t) {
      f32x4 z4 = {0.f, 0.f, 0.f, 0.f};
      z4 = __builtin_amdgcn_mfma_f32_16x16x32_bf16(a0, bfrag[t][0], z4, 0, 0, 0);
      acc[t] = __builtin_amdgcn_mfma_f32_16x16x32_bf16(a1, bfrag[t][1], z4, 0, 0, 0);
    }

#pragma unroll
    for (int r = 0; r < 4; ++r) {
      int node = node0 + quad * 4 + r;
      if (node >= n) break;
      size_t rb = (size_t)node * 64 + m;
#pragma unroll
      for (int t = 0; t < 4; ++t) y[rb + t * 16] = bf16c(acc[t][r]);
#pragma unroll
      for (int t = 0; t < 4; ++t) zout[rb + t * 16] = bf16c(acc[t + 4][r] + bias[t]);
    }
  }
}

// ---- aggregate: z[node] = relu(mean_nbr(y) + z[node]); y,z bf16 rows (128B).
// 4 nodes/wave: 16-lane groups; sub picks row of a slot pair; 8 lanes x uint4
// = one full row. Slots 0..31 fully unrolled with per-slot predication
// (masked lanes issue no memory op). Rare slots 32..63 keep the dynamic path.
__global__ __launch_bounds__(256) void k_aggr(
    const unsigned short* __restrict__ yb, const int* __restrict__ cnt,
    const int* __restrict__ colp, unsigned short* zio, int n) {
  const unsigned int* y = (const unsigned int*)yb;  // 2 bf16 per u32; row = 32 u32
  int lane = threadIdx.x & 63;
  int wv = (blockIdx.x * blockDim.x + threadIdx.x) >> 6;
  int g16 = lane & 48;       // group base lane
  int lig = lane & 15;       // lane in group
  int sub = lig >> 3;        // which row of the current slot pair
  int fo = (lig & 7) * 4;    // u32 offset in row

  int node = (wv << 2) + (g16 >> 4);
  bool act = node < n;
  int cn = act ? node : 0;
  int deg = cnt[cn];
  int jcap = deg < 64 ? deg : 64;
  size_t crow = (size_t)cn << 6;
  int cidxA = colp[crow + lig];
  int cidxB = colp[crow + 16 + lig];

  int wmax = jcap;
  wmax = max(wmax, __shfl_xor(wmax, 16, 64));
  wmax = max(wmax, __shfl_xor(wmax, 32, 64));

  f32x2 acc[4];
#pragma unroll
  for (int k = 0; k < 4; ++k) acc[k] = (f32x2){0.f, 0.f};

#define ACCUM(U)                                             \
  do {                                                       \
    acc[0] += (f32x2){bflo((U).x), bfhi((U).x)};             \
    acc[1] += (f32x2){bflo((U).y), bfhi((U).y)};             \
    acc[2] += (f32x2){bflo((U).z), bfhi((U).z)};             \
    acc[3] += (f32x2){bflo((U).w), bfhi((U).w)};             \
  } while (0)

  // slots 0..15: full unroll, predicated loads (no BW cost for masked lanes)
#pragma unroll
  for (int s = 0; s < 16; s += 2) {
    int slot = s + sub;
    int c = __shfl(cidxA, g16 | slot, 64);
    if (slot < jcap) {
      uint4 v = *(const uint4*)(y + ((size_t)c << 5) + fo);
      ACCUM(v);
    }
  }
  if (wmax > 16) {  // slots 16..31: full unroll, predicated
#pragma unroll
    for (int s = 0; s < 16; s += 2) {
      int slot = s + sub;
      int c = __shfl(cidxB, g16 | slot, 64);
      if (slot + 16 < jcap) {
        uint4 v = *(const uint4*)(y + ((size_t)c << 5) + fo);
        ACCUM(v);
      }
    }
  }
  if (wmax > 32) {  // rare: slots 32..63
    int cidxC = colp[crow + 32 + lig];
    int cidxD = colp[crow + 48 + lig];
    {
      int lim = (wmax < 48 ? wmax : 48) - 32;
      for (int s = 0; s < lim; s += 2) {
        int slot = s + sub;
        int c = __shfl(cidxC, g16 | slot, 64);
        if (slot + 32 < jcap) {
          uint4 v = *(const uint4*)(y + ((size_t)c << 5) + fo);
          ACCUM(v);
        }
      }
    }
    if (wmax > 48) {
      int lim = wmax - 48;
      for (int s = 0; s < lim; s += 2) {
        int slot = s + sub;
        int c = __shfl(cidxD, g16 | slot, 64);
        if (slot + 48 < jcap) {
          uint4 v = *(const uint4*)(y + ((size_t)c << 5) + fo);
          ACCUM(v);
        }
      }
    }
  }
#undef ACCUM

#pragma unroll
  for (int k = 0; k < 4; ++k) {
    acc[k].x += __shfl_xor(acc[k].x, 8, 64);
    acc[k].y += __shfl_xor(acc[k].y, 8, 64);
  }

  if (act && sub == 0) {  // 8 lanes/group: lane owns u32s fo..fo+3 = feats 2fo..2fo+7
    float inv = (deg > 0) ? 1.0f / (float)deg : 0.f;
    unsigned int* zp = (unsigned int*)(zio + ((size_t)node << 6)) + fo;
    uint4 zv = *(uint4*)zp;
    zv.x = bfpk(fmaxf(fmaf(acc[0].x, inv, bflo(zv.x)), 0.f),
                fmaxf(fmaf(acc[0].y, inv, bfhi(zv.x)), 0.f));
    zv.y = bfpk(fmaxf(fmaf(acc[1].x, inv, bflo(zv.y)), 0.f),
                fmaxf(fmaf(acc[1].y, inv, bfhi(zv.y)), 0.f));
    zv.z = bfpk(fmaxf(fmaf(acc[2].x, inv, bflo(zv.z)), 0.f),
                fmaxf(fmaf(acc[2].y, inv, bfhi(zv.z)), 0.f));
    zv.w = bfpk(fmaxf(fmaf(acc[3].x, inv, bflo(zv.w)), 0.f),
                fmaxf(fmaf(acc[3].y, inv, bfhi(zv.w)), 0.f));
    *(uint4*)zp = zv;
  }
}

// ---- head: logits = h2(bf16) @ bf16(Wout)^T + bout; log_softmax -> fp32 out.
__global__ __launch_bounds__(256) void k_out(
    const unsigned short* __restrict__ h, const float* __restrict__ Wo,
    const float* __restrict__ bo, float* __restrict__ out, int n) {
  int lane = threadIdx.x & 63;
  int quad = lane >> 4, m = lane & 15;
  int w0 = (blockIdx.x * blockDim.x + threadIdx.x) >> 6;
  int nw = (gridDim.x * blockDim.x) >> 6;

  bf16x8 bfrag[4][2];
  float bias[4];
#pragma unroll
  for (int t = 0; t < 4; ++t) {
    int row = t * 16 + m;
#pragma unroll
    for (int s = 0; s < 2; ++s)
      bfrag[t][s] = ld_bf8(Wo + row * 64 + s * 32 + quad * 8);
    bias[t] = bo[t * 16 + m];
  }

  int nT = (n + 15) >> 4;
  for (int tile = w0; tile < nT; tile += nw) {
    int node0 = tile << 4;
    int mrow = node0 + m;
    if (mrow >= n) mrow = n - 1;
    const unsigned short* xr = h + (size_t)mrow * 64;
    bf16x8 a0 = *(const bf16x8*)(xr + quad * 8);
    bf16x8 a1 = *(const bf16x8*)(xr + 32 + quad * 8);

    f32x4 acc[4];
#pragma unroll
    for (int t = 0; t < 4; ++t) {
      f32x4 z4 = {0.f, 0.f, 0.f, 0.f};
      z4 = __builtin_amdgcn_mfma_f32_16x16x32_bf16(a0, bfrag[t][0], z4, 0, 0, 0);
      acc[t] = __builtin_amdgcn_mfma_f32_16x16x32_bf16(a1, bfrag[t][1], z4, 0, 0, 0);
    }

#pragma unroll
    for (int r = 0; r < 4; ++r) {
      int node = node0 + quad * 4 + r;
      if (node >= n) break;
      float l0 = acc[0][r] + bias[0];
      float l1 = acc[1][r] + bias[1];
      float l2 = acc[2][r] + bias[2];
      float l3 = acc[3][r] + bias[3];
      float mx = fmaxf(fmaxf(l0, l1), fmaxf(l2, l3));
#pragma unroll
      for (int off = 1; off <= 8; off <<= 1) mx = fmaxf(mx, __shfl_xor(mx, off, 64));
      float s = expf(l0 - mx) + expf(l1 - mx) + expf(l2 - mx) + expf(l3 - mx);
#pragma unroll
      for (int off = 1; off <= 8; off <<= 1) s += __shfl_xor(s, off, 64);
      float ls = logf(s);
      size_t rb = (size_t)node * 64 + m;
      out[rb + 0]  = l0 - mx - ls;
      out[rb + 16] = l1 - mx - ls;
      out[rb + 32] = l2 - mx - ls;
      out[rb + 48] = l3 - mx - ls;
    }
  }
}

extern "C" void kernel_launch(void* const* d_in, const int* in_sizes, int n_in,
                              void* d_out, int out_size, void* d_ws, size_t ws_size,
                              hipStream_t stream) {
  const float* x    = (const float*)d_in[0];
  const int*   ei   = (const int*)d_in[1];
  const float* W1l  = (const float*)d_in[2];
  const float* b1l  = (const float*)d_in[3];
  const float* W1r  = (const float*)d_in[4];
  const float* W2l  = (const float*)d_in[5];
  const float* b2l  = (const float*)d_in[6];
  const float* W2r  = (const float*)d_in[7];
  const float* Wout = (const float*)d_in[8];
  const float* bout = (const float*)d_in[9];
  int N = in_sizes[0] / 64;
  int E = in_sizes[1] / 2;
  int NB = (N + 127) >> 7;  // 128-node buckets; NB=782 <= NBPAD

  char* p = (char*)d_ws;
  auto carve = [&](size_t bytes) {
    char* r = p;
    p += (bytes + 255) & ~(size_t)255;
    return r;
  };
  int* cellcnt       = (int*)carve((size_t)NBINA * NBPAD * 4);   // 1 MB
  int* cnt           = (int*)carve((size_t)NB * 128 * 4);        // padded
  int* colp          = (int*)carve((size_t)NB * 128 * 64 * 4);   // padded
  unsigned short* y  = (unsigned short*)carve((size_t)N * 64 * 2);
  unsigned short* z  = (unsigned short*)carve((size_t)N * 64 * 2);
  unsigned int* bucketData = (unsigned int*)carve((size_t)NB * NBINA * CAPC * 4);  // 25.6 MB

  int aggr_blocks = (N + 15) / 16;  // 4 nodes/wave, 4 waves/block
  // front-end: each kernel at its best-measured shape, no fusion
  k_binA<<<NBINA, TBA, 0, stream>>>(ei, E, cellcnt, bucketData, NB);
  k_binB<<<NB, TB, 0, stream>>>(bucketData, cellcnt, colp, cnt);
  k_xform_f32<<<XFB, TB, 0, stream>>>(x, W1l, W1r, b1l, y, z, N);
  k_aggr<<<aggr_blocks, TB, 0, stream>>>(y, cnt, colp, z, N);  // z = h1 (bf16)
  // layer 2 (reads z in place; y buffer reused)
  k_xform_b16<<<XFB, TB, 0, stream>>>(z, W2l, W2r, b2l, y, z, N);
  k_aggr<<<aggr_blocks, TB, 0, stream>>>(y, cnt, colp, z, N);  // z = h2 (bf16)
  // head
  k_out<<<XFB, TB, 0, stream>>>(z, Wout, bout, (float*)d_out, N);
}